// Round 1
// baseline (1307.892 us; speedup 1.0000x reference)
//
#include <hip/hip_runtime.h>
#include <math.h>

#define N_NODES 100000
#define N_EDGES 3200000
#define INC 128
#define HID 64

constexpr int BLK = 256;
constexpr int NBLK_N = (N_NODES + BLK - 1) / BLK;   // 391
constexpr int NBLK_E = (N_EDGES + BLK - 1) / BLK;   // 12500

__global__ void zero_i(int* p, int n) {
    int i = blockIdx.x * blockDim.x + threadIdx.x;
    if (i < n) p[i] = 0;
}
__global__ void zero_f(float* p, int n) {
    int i = blockIdx.x * blockDim.x + threadIdx.x;
    if (i < n) p[i] = 0.f;
}

__global__ void count_deg(const int* __restrict__ dst, int* __restrict__ counts, int e) {
    int i = blockIdx.x * blockDim.x + threadIdx.x;
    if (i < e) atomicAdd(&counts[dst[i]], 1);
}

// block-level exclusive scan (within block), block totals to bsums
__global__ void scan1(const int* __restrict__ counts, int* __restrict__ offsets,
                      int* __restrict__ bsums, int n) {
    __shared__ int s[BLK];
    int i = blockIdx.x * BLK + threadIdx.x;
    int v = (i < n) ? counts[i] : 0;
    s[threadIdx.x] = v;
    __syncthreads();
    for (int d = 1; d < BLK; d <<= 1) {
        int t = (threadIdx.x >= d) ? s[threadIdx.x - d] : 0;
        __syncthreads();
        s[threadIdx.x] += t;
        __syncthreads();
    }
    if (i < n) offsets[i] = s[threadIdx.x] - v;  // exclusive
    if (threadIdx.x == BLK - 1) bsums[blockIdx.x] = s[BLK - 1];
}

// single-block exclusive scan of block sums (nb <= 512)
__global__ void scan2(int* __restrict__ bsums, int nb) {
    __shared__ int s[512];
    int v = (threadIdx.x < nb) ? bsums[threadIdx.x] : 0;
    s[threadIdx.x] = v;
    __syncthreads();
    for (int d = 1; d < 512; d <<= 1) {
        int t = (threadIdx.x >= d) ? s[threadIdx.x - d] : 0;
        __syncthreads();
        s[threadIdx.x] += t;
        __syncthreads();
    }
    if (threadIdx.x < nb) bsums[threadIdx.x] = s[threadIdx.x] - v;
}

__global__ void scan3(const int* __restrict__ counts, int* __restrict__ offsets,
                      int* __restrict__ cursor, const int* __restrict__ bsums, int n) {
    int i = blockIdx.x * BLK + threadIdx.x;
    if (i < n) {
        int o = offsets[i] + bsums[blockIdx.x];
        offsets[i] = o;
        cursor[i] = o;
        if (i == n - 1) offsets[n] = o + counts[i];
    }
}

__global__ void fill_csr(const int* __restrict__ src, const int* __restrict__ dst,
                         const float* __restrict__ ew, int* __restrict__ cursor,
                         int* __restrict__ csr_src, float* __restrict__ csr_ew, int e) {
    int i = blockIdx.x * blockDim.x + threadIdx.x;
    if (i < e) {
        int d = dst[i];
        int pos = atomicAdd(&cursor[d], 1);
        csr_src[pos] = src[i];
        csr_ew[pos] = ew[i];
    }
}

// One wave (64 lanes) per destination node; lane = channel.
// out[n] = relu( sum_e ew[e] * t[src[e]] + bias )
__global__ __launch_bounds__(BLK) void aggregate(
    const float* __restrict__ t, const int* __restrict__ offs,
    const int* __restrict__ csr_src, const float* __restrict__ csr_ew,
    const float* __restrict__ bias, float* __restrict__ out, int n)
{
    int wave = blockIdx.x * (BLK / 64) + (threadIdx.x >> 6);
    int lane = threadIdx.x & 63;
    if (wave >= n) return;
    int s0 = offs[wave], s1 = offs[wave + 1];
    float acc = 0.f;
    for (int base = s0; base < s1; base += 64) {
        int idx = base + lane;
        int e = (idx < s1) ? idx : (s1 - 1);
        int srcv = csr_src[e];
        float eww = csr_ew[e];
        int cnt = min(64, s1 - base);
        for (int i = 0; i < cnt; ++i) {
            int s = __shfl(srcv, i, 64);
            float w = __shfl(eww, i, 64);
            acc += w * t[(size_t)s * HID + lane];
        }
    }
    out[(size_t)wave * HID + lane] = fmaxf(acc + bias[lane], 0.f);
}

// per-channel sum and sumsq over rows -> stats[0..63]=sum, stats[64..127]=sumsq
__global__ __launch_bounds__(BLK) void bn_stats(const float* __restrict__ h,
                                                float* __restrict__ stats, int n) {
    int c = threadIdx.x & 63;
    int rb = threadIdx.x >> 6;  // 0..3
    float s = 0.f, s2 = 0.f;
    for (int r = blockIdx.x * 4 + rb; r < n; r += gridDim.x * 4) {
        float v = h[(size_t)r * HID + c];
        s += v;
        s2 += v * v;
    }
    __shared__ float ls[4][64], ls2[4][64];
    ls[rb][c] = s;
    ls2[rb][c] = s2;
    __syncthreads();
    if (threadIdx.x < 64) {
        int cc = threadIdx.x;
        float a = ls[0][cc] + ls[1][cc] + ls[2][cc] + ls[3][cc];
        float b = ls2[0][cc] + ls2[1][cc] + ls2[2][cc] + ls2[3][cc];
        atomicAdd(&stats[cc], a);
        atomicAdd(&stats[64 + cc], b);
    }
}

__global__ void bn_finalize(const float* __restrict__ stats, const float* __restrict__ g,
                            const float* __restrict__ be, float* __restrict__ scsh, float n) {
    int c = threadIdx.x;
    if (c < 64) {
        float mean = stats[c] / n;
        float var = stats[64 + c] / n - mean * mean;
        float s = 1.0f / sqrtf(var + 1e-5f);
        float sc = g[c] * s;
        scsh[c] = sc;
        scsh[64 + c] = be[c] - mean * sc;
    }
}

// Y[r,:] = act( (trans? X*sc+sh : X)[r,:] @ W (+ bias) )
// One thread per row; W staged in LDS (broadcast reads).
template <int IN, int OUT, bool TRANS, bool BIAS, int ACT>
__global__ __launch_bounds__(BLK) void mm_kernel(
    const float* __restrict__ X, const float* __restrict__ W,
    const float* __restrict__ bias,
    const float* __restrict__ scale, const float* __restrict__ shift,
    float* __restrict__ Y, int n)
{
    __shared__ float Wl[IN * OUT];
    for (int i = threadIdx.x; i < IN * OUT; i += BLK) Wl[i] = W[i];
    __shared__ float sc[IN], sh[IN];
    if (TRANS) {
        for (int i = threadIdx.x; i < IN; i += BLK) {
            sc[i] = scale[i];
            sh[i] = shift[i];
        }
    }
    __syncthreads();
    int r = blockIdx.x * BLK + threadIdx.x;
    if (r >= n) return;
    float acc[OUT];
#pragma unroll
    for (int j = 0; j < OUT; ++j) acc[j] = 0.f;
    const float4* x4 = reinterpret_cast<const float4*>(X + (size_t)r * IN);
#pragma unroll 2
    for (int k4 = 0; k4 < IN / 4; ++k4) {
        float4 xv = x4[k4];
        float xs[4] = {xv.x, xv.y, xv.z, xv.w};
#pragma unroll
        for (int u = 0; u < 4; ++u) {
            int k = k4 * 4 + u;
            float xk = xs[u];
            if (TRANS) xk = xk * sc[k] + sh[k];
#pragma unroll
            for (int j = 0; j < OUT; ++j) acc[j] += xk * Wl[k * OUT + j];
        }
    }
    float* yr = Y + (size_t)r * OUT;
#pragma unroll
    for (int j = 0; j < OUT; ++j) {
        float v = acc[j];
        if (BIAS) v += bias[j];
        if (ACT == 1) v = 0.5f * v * (1.0f + erff(v * 0.70710678118654752f));
        yr[j] = v;
    }
}

extern "C" void kernel_launch(void* const* d_in, const int* in_sizes, int n_in,
                              void* d_out, int out_size, void* d_ws, size_t ws_size,
                              hipStream_t stream)
{
    const float* x   = (const float*)d_in[0];
    const int*   ei  = (const int*)d_in[1];
    const int*   srcs = ei;
    const int*   dsts = ei + N_EDGES;
    const float* ew  = (const float*)d_in[2];
    const float* cw0 = (const float*)d_in[3];  const float* cb0 = (const float*)d_in[4];
    const float* cw1 = (const float*)d_in[5];  const float* cb1 = (const float*)d_in[6];
    const float* cw2 = (const float*)d_in[7];  const float* cb2 = (const float*)d_in[8];
    const float* g0  = (const float*)d_in[9];  const float* be0 = (const float*)d_in[10];
    const float* g1  = (const float*)d_in[11]; const float* be1 = (const float*)d_in[12];
    const float* g2  = (const float*)d_in[13]; const float* be2 = (const float*)d_in[14];
    const float* mw1 = (const float*)d_in[15]; const float* mb1 = (const float*)d_in[16];
    const float* mw2 = (const float*)d_in[17]; const float* mb2 = (const float*)d_in[18];
    const float* mw3 = (const float*)d_in[19]; const float* mb3 = (const float*)d_in[20];
    float* out = (float*)d_out;

    char* ws = (char*)d_ws;
    size_t off = 0;
    auto alloc = [&](size_t b) { size_t o = off; off = (off + b + 511) & ~(size_t)511; return o; };

    int*   counts  = (int*)(ws + alloc((size_t)N_NODES * 4));
    int*   offsets = (int*)(ws + alloc((size_t)(N_NODES + 1) * 4));
    int*   cursor  = (int*)(ws + alloc((size_t)N_NODES * 4));
    int*   bsums   = (int*)(ws + alloc((size_t)NBLK_N * 4));
    float* stats   = (float*)(ws + alloc(128 * 4));
    float* scsh    = (float*)(ws + alloc(128 * 4));
    size_t o_csr   = alloc((size_t)N_EDGES * 4);
    int*   csr_src = (int*)(ws + o_csr);
    float* csr_ew  = (float*)(ws + alloc((size_t)N_EDGES * 4));
    float* t       = (float*)(ws + alloc((size_t)N_NODES * HID * 4));
    float* h       = (float*)(ws + alloc((size_t)N_NODES * HID * 4));
    // hb (N x 128) aliases csr_src + csr_ew + t: those are dead by the time hb is used
    float* hb      = (float*)(ws + o_csr);

    // ---- Build CSR by destination (once per call) ----
    zero_i<<<NBLK_N, BLK, 0, stream>>>(counts, N_NODES);
    count_deg<<<NBLK_E, BLK, 0, stream>>>(dsts, counts, N_EDGES);
    scan1<<<NBLK_N, BLK, 0, stream>>>(counts, offsets, bsums, N_NODES);
    scan2<<<1, 512, 0, stream>>>(bsums, NBLK_N);
    scan3<<<NBLK_N, BLK, 0, stream>>>(counts, offsets, cursor, bsums, N_NODES);
    fill_csr<<<NBLK_E, BLK, 0, stream>>>(srcs, dsts, ew, cursor, csr_src, csr_ew, N_EDGES);

    const int AGG_BLOCKS = N_NODES * 64 / BLK;  // 25000

    // ---- Layer 0 ----
    mm_kernel<INC, HID, false, false, 0><<<NBLK_N, BLK, 0, stream>>>(x, cw0, nullptr, nullptr, nullptr, t, N_NODES);
    aggregate<<<AGG_BLOCKS, BLK, 0, stream>>>(t, offsets, csr_src, csr_ew, cb0, h, N_NODES);
    zero_f<<<1, 128, 0, stream>>>(stats, 128);
    bn_stats<<<512, BLK, 0, stream>>>(h, stats, N_NODES);
    bn_finalize<<<1, 64, 0, stream>>>(stats, g0, be0, scsh, (float)N_NODES);

    // ---- Layer 1 (BN folded into matmul input) ----
    mm_kernel<HID, HID, true, false, 0><<<NBLK_N, BLK, 0, stream>>>(h, cw1, nullptr, scsh, scsh + 64, t, N_NODES);
    aggregate<<<AGG_BLOCKS, BLK, 0, stream>>>(t, offsets, csr_src, csr_ew, cb1, h, N_NODES);
    zero_f<<<1, 128, 0, stream>>>(stats, 128);
    bn_stats<<<512, BLK, 0, stream>>>(h, stats, N_NODES);
    bn_finalize<<<1, 64, 0, stream>>>(stats, g1, be1, scsh, (float)N_NODES);

    // ---- Layer 2 ----
    mm_kernel<HID, HID, true, false, 0><<<NBLK_N, BLK, 0, stream>>>(h, cw2, nullptr, scsh, scsh + 64, t, N_NODES);
    aggregate<<<AGG_BLOCKS, BLK, 0, stream>>>(t, offsets, csr_src, csr_ew, cb2, h, N_NODES);
    zero_f<<<1, 128, 0, stream>>>(stats, 128);
    bn_stats<<<512, BLK, 0, stream>>>(h, stats, N_NODES);
    bn_finalize<<<1, 64, 0, stream>>>(stats, g2, be2, scsh, (float)N_NODES);

    // ---- MLP (BN of layer 2 folded into first matmul) ----
    mm_kernel<HID, 2 * HID, true, true, 1><<<NBLK_N, BLK, 0, stream>>>(h, mw1, mb1, scsh, scsh + 64, hb, N_NODES);
    mm_kernel<2 * HID, HID, false, true, 1><<<NBLK_N, BLK, 0, stream>>>(hb, mw2, mb2, nullptr, nullptr, h, N_NODES);
    mm_kernel<HID, 5, false, true, 0><<<NBLK_N, BLK, 0, stream>>>(h, mw3, mb3, nullptr, nullptr, out, N_NODES);
}